// Round 1
// baseline (1090.728 us; speedup 1.0000x reference)
//
#include <hip/hip_runtime.h>

#define EPS 1e-3f
constexpr int K = 16;
constexpr int CH_BLK = 128;        // channels per sums-block
constexpr int ROWS_PER_BLK = 512;  // rows per sums-block

// ---------------- kernel 1: per-context counts ----------------
__global__ __launch_bounds__(256) void count_kernel(const int* __restrict__ ctx,
                                                    int N, float* __restrict__ counts) {
    __shared__ float cnt[K];
    int t = threadIdx.x;
    if (t < K) cnt[t] = 0.f;
    __syncthreads();
    for (int i = blockIdx.x * blockDim.x + t; i < N; i += gridDim.x * blockDim.x)
        atomicAdd(&cnt[ctx[i]], 1.f);
    __syncthreads();
    if (t < K) atomicAdd(&counts[t], cnt[t]);
}

// ---------------- kernel 2: segment sums (s1, s2) ----------------
// LDS layout permutation: channel c stored at (c&3)*32 + (c>>2) within the
// 128-channel slot. For a float4 load (c = tx*4 + j) the atomic address is
// k*128 + j*32 + tx  ->  bank = tx  -> 2 lanes/bank across a wave (free).
__global__ __launch_bounds__(256) void sums_kernel(const float* __restrict__ x,
                                                   const int* __restrict__ ctx,
                                                   int N, int C,
                                                   float* __restrict__ s1g,
                                                   float* __restrict__ s2g) {
    __shared__ float s1[K * CH_BLK];
    __shared__ float s2[K * CH_BLK];
    int t = threadIdx.x;
    for (int i = t; i < K * CH_BLK; i += 256) { s1[i] = 0.f; s2[i] = 0.f; }
    __syncthreads();

    int colBlks = C / CH_BLK;
    int colBlk = blockIdx.x % colBlks;
    int rowBlk = blockIdx.x / colBlks;
    int c0 = colBlk * CH_BLK;
    int r0 = rowBlk * ROWS_PER_BLK;
    int rEnd = min(r0 + ROWS_PER_BLK, N);

    int tx = t & 31;   // float4 index within the 128-channel slice
    int ty = t >> 5;   // 8 rows in flight

    for (int r = r0 + ty; r < rEnd; r += 8) {
        int k = ctx[r];
        const float4 v = *reinterpret_cast<const float4*>(x + (size_t)r * C + c0 + tx * 4);
        float* p1 = s1 + k * CH_BLK + tx;
        float* p2 = s2 + k * CH_BLK + tx;
        atomicAdd(p1 + 0 * 32, v.x);
        atomicAdd(p1 + 1 * 32, v.y);
        atomicAdd(p1 + 2 * 32, v.z);
        atomicAdd(p1 + 3 * 32, v.w);
        atomicAdd(p2 + 0 * 32, v.x * v.x);
        atomicAdd(p2 + 1 * 32, v.y * v.y);
        atomicAdd(p2 + 2 * 32, v.z * v.z);
        atomicAdd(p2 + 3 * 32, v.w * v.w);
    }
    __syncthreads();

    for (int i = t; i < K * CH_BLK; i += 256) {
        int k = i >> 7;          // / CH_BLK
        int c = i & (CH_BLK - 1);
        int p = k * CH_BLK + ((c & 3) << 5) + (c >> 2);
        atomicAdd(&s1g[k * C + c0 + c], s1[p]);
        atomicAdd(&s2g[k * C + c0 + c], s2[p]);
    }
}

// ---------------- kernel 3: fused affine coefficients ----------------
__global__ __launch_bounds__(256) void finalize_kernel(const float* __restrict__ s1,
                                                       const float* __restrict__ s2,
                                                       const float* __restrict__ counts,
                                                       const float* __restrict__ gamma,
                                                       const float* __restrict__ beta,
                                                       const float* __restrict__ priors,
                                                       float* __restrict__ w,
                                                       float* __restrict__ b, int C) {
    int i = blockIdx.x * blockDim.x + threadIdx.x;
    if (i >= K * C) return;
    int k = i / C;
    float n = counts[k];
    float sn = fmaxf(n, 1.f);
    float mean = s1[i] / sn;
    float var = s2[i] / sn - mean * mean;
    float inv = rsqrtf(var + EPS);
    float ps = rsqrtf(priors[k]);
    float wi, bi;
    if (n > 0.f) {
        wi = gamma[i] * inv * ps;
        bi = (beta[i] - gamma[i] * mean * inv) * ps;
    } else {                 // empty context: pass-through
        wi = 1.f;
        bi = 0.f;
    }
    w[i] = wi;
    b[i] = bi;
}

// ---------------- kernel 4: apply ----------------
__global__ __launch_bounds__(256) void apply_kernel(const float* __restrict__ x,
                                                    const int* __restrict__ ctx,
                                                    const float* __restrict__ w,
                                                    const float* __restrict__ b,
                                                    float* __restrict__ out,
                                                    int N, int C) {
    unsigned C4 = (unsigned)(C >> 2);
    unsigned total = (unsigned)N * C4;
    for (unsigned i = blockIdx.x * blockDim.x + threadIdx.x; i < total;
         i += gridDim.x * blockDim.x) {
        unsigned row = i / C4;
        unsigned c4 = i - row * C4;
        int k = ctx[row];
        float4 v = reinterpret_cast<const float4*>(x)[i];
        float4 ww = reinterpret_cast<const float4*>(w + (size_t)k * C)[c4];
        float4 bb = reinterpret_cast<const float4*>(b + (size_t)k * C)[c4];
        float4 o;
        o.x = v.x * ww.x + bb.x;
        o.y = v.y * ww.y + bb.y;
        o.z = v.z * ww.z + bb.z;
        o.w = v.w * ww.w + bb.w;
        reinterpret_cast<float4*>(out)[i] = o;
    }
}

extern "C" void kernel_launch(void* const* d_in, const int* in_sizes, int n_in,
                              void* d_out, int out_size, void* d_ws, size_t ws_size,
                              hipStream_t stream) {
    const float* samples  = (const float*)d_in[0];
    const int*   contexts = (const int*)d_in[1];
    const float* gamma    = (const float*)d_in[2];
    const float* beta     = (const float*)d_in[3];
    const float* priors   = (const float*)d_in[4];

    int N = in_sizes[1];
    int C = in_sizes[0] / N;   // 512

    float* ws     = (float*)d_ws;
    float* s1     = ws;                    // K*C
    float* s2     = ws + K * C;            // K*C
    float* counts = ws + 2 * K * C;        // K (padded to 64)
    float* w      = ws + 2 * K * C + 64;   // K*C, 16B aligned
    float* b      = w + K * C;             // K*C

    // zero accumulators (ws is poisoned 0xAA before every call)
    hipMemsetAsync(d_ws, 0, (size_t)(2 * K * C + 64) * sizeof(float), stream);

    count_kernel<<<256, 256, 0, stream>>>(contexts, N, counts);

    int colBlks = C / CH_BLK;
    int rowBlks = (N + ROWS_PER_BLK - 1) / ROWS_PER_BLK;
    sums_kernel<<<rowBlks * colBlks, 256, 0, stream>>>(samples, contexts, N, C, s1, s2);

    finalize_kernel<<<(K * C + 255) / 256, 256, 0, stream>>>(s1, s2, counts, gamma, beta,
                                                             priors, w, b, C);

    apply_kernel<<<2048, 256, 0, stream>>>(samples, contexts, w, b, (float*)d_out, N, C);
}